// Round 3
// baseline (207.579 us; speedup 1.0000x reference)
//
#include <hip/hip_runtime.h>
#include <hip/hip_bf16.h>
#include <stdint.h>

#define B_ 32
#define L_ 8192
#define D_ 512

// K1: scores[b][l] = sum_d q[b][d] * k[b][l][d]   (fp32 inputs)
// grid = B_*(L_/64) = 4096 blocks, block = 256 (4 waves), each wave 16 rows.
// Per row: 64 lanes x 2 float4 = 512 floats = the whole D.
__global__ __launch_bounds__(256) void k_scores(const float* __restrict__ q,
                                                const float* __restrict__ k,
                                                float* __restrict__ scores) {
    int blk  = blockIdx.x;
    int b    = blk >> 7;            // 128 chunks per batch
    int l0   = (blk & 127) << 6;    // chunk * 64 rows
    int wave = threadIdx.x >> 6;
    int lane = threadIdx.x & 63;

    float4 q0 = *reinterpret_cast<const float4*>(q + b * D_ + lane * 4);
    float4 q1 = *reinterpret_cast<const float4*>(q + b * D_ + 256 + lane * 4);

    const size_t kbase = (size_t)b * L_ * D_;
    for (int i = 0; i < 16; i++) {
        int l = l0 + i * 4 + wave;  // 4 waves read 4 adjacent 2 KiB rows
        const float* kr = k + kbase + (size_t)l * D_;
        float4 a0 = *reinterpret_cast<const float4*>(kr + lane * 4);
        float4 a1 = *reinterpret_cast<const float4*>(kr + 256 + lane * 4);
        float s = a0.x * q0.x + a0.y * q0.y + a0.z * q0.z + a0.w * q0.w
                + a1.x * q1.x + a1.y * q1.y + a1.z * q1.z + a1.w * q1.w;
        #pragma unroll
        for (int off = 32; off; off >>= 1) s += __shfl_xor(s, off, 64);
        if (lane == 0) scores[b * L_ + l] = s;
    }
}

// K2: double softmax over L per batch. 32 blocks x 1024 threads, 8 elems/thread.
// Overwrites scores with att (fp32) and also writes att (fp32) to d_out.
__global__ __launch_bounds__(1024) void k_softmax2(float* __restrict__ sc,
                                                   float* __restrict__ att_out) {
    int b = blockIdx.x;
    int t = threadIdx.x;
    int wid = t >> 6, lane = t & 63;
    __shared__ float red[16];

    float s[8];
    #pragma unroll
    for (int j = 0; j < 8; j++) s[j] = sc[b * L_ + t + j * 1024];

    // ---- max over L ----
    float m = s[0];
    #pragma unroll
    for (int j = 1; j < 8; j++) m = fmaxf(m, s[j]);
    #pragma unroll
    for (int off = 32; off; off >>= 1) m = fmaxf(m, __shfl_xor(m, off, 64));
    if (lane == 0) red[wid] = m;
    __syncthreads();
    m = red[0];
    #pragma unroll
    for (int i = 1; i < 16; i++) m = fmaxf(m, red[i]);
    __syncthreads();

    // ---- Z = sum exp(s - m) ----
    float e[8]; float sum = 0.f;
    #pragma unroll
    for (int j = 0; j < 8; j++) { e[j] = expf(s[j] - m); sum += e[j]; }
    #pragma unroll
    for (int off = 32; off; off >>= 1) sum += __shfl_xor(sum, off, 64);
    if (lane == 0) red[wid] = sum;
    __syncthreads();
    float Z = 0.f;
    #pragma unroll
    for (int i = 0; i < 16; i++) Z += red[i];
    __syncthreads();

    float invZ = 1.f / Z;
    // max of att_weights sits at the argmax of scores: exp(0)/Z = invZ
    float maxw = invZ;

    // ---- second softmax ----
    float p[8]; float sum2 = 0.f;
    #pragma unroll
    for (int j = 0; j < 8; j++) { p[j] = expf(e[j] * invZ - maxw); sum2 += p[j]; }
    #pragma unroll
    for (int off = 32; off; off >>= 1) sum2 += __shfl_xor(sum2, off, 64);
    if (lane == 0) red[wid] = sum2;
    __syncthreads();
    float S2 = 0.f;
    #pragma unroll
    for (int i = 0; i < 16; i++) S2 += red[i];

    float invS2 = 1.f / S2;
    #pragma unroll
    for (int j = 0; j < 8; j++) {
        float a = p[j] * invS2;
        int idx = b * L_ + t + j * 1024;
        sc[idx] = a;       // fp32 att for ctx pass (ws)
        att_out[idx] = a;  // fp32 att output
    }
}

// K3: deterministic partial ctx sums (fp32 V). grid = B_*32, block 256.
// Block = (b, chunk c of 256 L-rows). Threads 0..127 do even rows, 128..255 odd.
// Thread covers d = (t&127)*4 .. +3; 128 threads x float4 = full D row, coalesced.
__global__ __launch_bounds__(256) void k_ctx_partial(const float* __restrict__ v,
                                                     const float* __restrict__ att,
                                                     float* __restrict__ part) {
    int blk  = blockIdx.x;
    int b    = blk >> 5;
    int c    = blk & 31;
    int t    = threadIdx.x;
    int half = t >> 7;            // 0 or 1
    int dt   = (t & 127) * 4;

    float acc[4] = {0.f, 0.f, 0.f, 0.f};
    const size_t vbase = (size_t)b * L_ * D_;
    int lbase = c * 256 + half;
    for (int i = 0; i < 128; i++) {
        int l = lbase + i * 2;
        float a = att[b * L_ + l];
        float4 vv = *reinterpret_cast<const float4*>(v + vbase + (size_t)l * D_ + dt);
        acc[0] += a * vv.x; acc[1] += a * vv.y;
        acc[2] += a * vv.z; acc[3] += a * vv.w;
    }
    float* dst = part + ((size_t)(b * 64 + c * 2 + half)) * D_ + dt;
    dst[0] = acc[0]; dst[1] = acc[1]; dst[2] = acc[2]; dst[3] = acc[3];
}

// K4: ctx[b][d] = sum over 64 partial rows; store fp32.
__global__ __launch_bounds__(512) void k_ctx_reduce(const float* __restrict__ part,
                                                    float* __restrict__ ctx) {
    int b = blockIdx.x;
    int d = threadIdx.x;
    float s = 0.f;
    for (int r = 0; r < 64; r++) s += part[((size_t)(b * 64 + r)) * D_ + d];
    ctx[b * D_ + d] = s;
}

extern "C" void kernel_launch(void* const* d_in, const int* in_sizes, int n_in,
                              void* d_out, int out_size, void* d_ws, size_t ws_size,
                              hipStream_t stream) {
    const float* q = (const float*)d_in[0];
    const float* k = (const float*)d_in[1];
    const float* v = (const float*)d_in[2];
    float* out     = (float*)d_out;
    float* ctx_out = out;              // 32*512 fp32
    float* att_out = out + B_ * D_;    // 32*8192 fp32

    float* scores = (float*)d_ws;      // B_*L_ fp32 = 1 MiB (becomes att fp32)
    float* part   = scores + B_ * L_;  // 32*64*512 fp32 = 4 MiB

    k_scores     <<<B_ * (L_ / 64), 256, 0, stream>>>(q, k, scores);
    k_softmax2   <<<B_,             1024, 0, stream>>>(scores, att_out);
    k_ctx_partial<<<B_ * 32,        256,  0, stream>>>(v, scores, part);
    k_ctx_reduce <<<B_,             512,  0, stream>>>(part, ctx_out);
}

// Round 4
// 201.851 us; speedup vs baseline: 1.0284x; 1.0284x over previous
//
#include <hip/hip_runtime.h>
#include <hip/hip_bf16.h>
#include <stdint.h>

#define B_ 32
#define L_ 8192
#define D_ 512

// K1: scores[b][l] = sum_d q[b][d] * k[b][l][d]   (fp32 inputs)
// grid = B_*(L_/64) = 4096 blocks, block = 256 (4 waves), each wave 16 rows.
// Per row: 64 lanes x 2 float4 = 512 floats = the whole D.
__global__ __launch_bounds__(256) void k_scores(const float* __restrict__ q,
                                                const float* __restrict__ k,
                                                float* __restrict__ scores) {
    int blk  = blockIdx.x;
    int b    = blk >> 7;            // 128 chunks per batch
    int l0   = (blk & 127) << 6;    // chunk * 64 rows
    int wave = threadIdx.x >> 6;
    int lane = threadIdx.x & 63;

    float4 q0 = *reinterpret_cast<const float4*>(q + b * D_ + lane * 4);
    float4 q1 = *reinterpret_cast<const float4*>(q + b * D_ + 256 + lane * 4);

    const size_t kbase = (size_t)b * L_ * D_;
    #pragma unroll 4
    for (int i = 0; i < 16; i++) {
        int l = l0 + i * 4 + wave;  // 4 waves read 4 adjacent 2 KiB rows
        const float* kr = k + kbase + (size_t)l * D_;
        float4 a0 = *reinterpret_cast<const float4*>(kr + lane * 4);
        float4 a1 = *reinterpret_cast<const float4*>(kr + 256 + lane * 4);
        float s = a0.x * q0.x + a0.y * q0.y + a0.z * q0.z + a0.w * q0.w
                + a1.x * q1.x + a1.y * q1.y + a1.z * q1.z + a1.w * q1.w;
        #pragma unroll
        for (int off = 32; off; off >>= 1) s += __shfl_xor(s, off, 64);
        if (lane == 0) scores[b * L_ + l] = s;
    }
}

// K2: double softmax over L per batch. 32 blocks x 1024 threads, 8 elems/thread.
// Writes att (fp32) to d_out only; also zeroes ctx[b] for K3's atomics.
__global__ __launch_bounds__(1024) void k_softmax2(const float* __restrict__ sc,
                                                   float* __restrict__ att_out,
                                                   float* __restrict__ ctx) {
    int b = blockIdx.x;
    int t = threadIdx.x;
    int wid = t >> 6, lane = t & 63;
    __shared__ float red[16];

    if (t < D_) ctx[b * D_ + t] = 0.f;   // stream-ordered before K3's atomicAdd

    float s[8];
    #pragma unroll
    for (int j = 0; j < 8; j++) s[j] = sc[b * L_ + t + j * 1024];

    // ---- max over L ----
    float m = s[0];
    #pragma unroll
    for (int j = 1; j < 8; j++) m = fmaxf(m, s[j]);
    #pragma unroll
    for (int off = 32; off; off >>= 1) m = fmaxf(m, __shfl_xor(m, off, 64));
    if (lane == 0) red[wid] = m;
    __syncthreads();
    m = red[0];
    #pragma unroll
    for (int i = 1; i < 16; i++) m = fmaxf(m, red[i]);
    __syncthreads();

    // ---- Z = sum exp(s - m) ----
    float e[8]; float sum = 0.f;
    #pragma unroll
    for (int j = 0; j < 8; j++) { e[j] = expf(s[j] - m); sum += e[j]; }
    #pragma unroll
    for (int off = 32; off; off >>= 1) sum += __shfl_xor(sum, off, 64);
    if (lane == 0) red[wid] = sum;
    __syncthreads();
    float Z = 0.f;
    #pragma unroll
    for (int i = 0; i < 16; i++) Z += red[i];
    __syncthreads();

    float invZ = 1.f / Z;
    // max of att_weights sits at the argmax of scores: exp(0)/Z = invZ
    float maxw = invZ;

    // ---- second softmax ----
    float p[8]; float sum2 = 0.f;
    #pragma unroll
    for (int j = 0; j < 8; j++) { p[j] = expf(e[j] * invZ - maxw); sum2 += p[j]; }
    #pragma unroll
    for (int off = 32; off; off >>= 1) sum2 += __shfl_xor(sum2, off, 64);
    if (lane == 0) red[wid] = sum2;
    __syncthreads();
    float S2 = 0.f;
    #pragma unroll
    for (int i = 0; i < 16; i++) S2 += red[i];

    float invS2 = 1.f / S2;
    #pragma unroll
    for (int j = 0; j < 8; j++) {
        att_out[b * L_ + t + j * 1024] = p[j] * invS2;
    }
}

// K3: ctx accumulation (fp32 V), fused reduction. grid = B_*32, block 256.
// Block = (b, chunk c of 256 L-rows). Threads 0..127 even rows, 128..255 odd.
// Thread covers d = (t&127)*4..+3. Block-level LDS reduce, then 4 atomicAdds
// per thread (t<128) into ctx — 32 blocks/b contend per address, ~1 us total.
__global__ __launch_bounds__(256) void k_ctx_partial(const float* __restrict__ v,
                                                     const float* __restrict__ att,
                                                     float* __restrict__ ctx) {
    int blk  = blockIdx.x;
    int b    = blk >> 5;
    int c    = blk & 31;
    int t    = threadIdx.x;
    int half = t >> 7;            // 0 or 1
    int dt   = (t & 127) * 4;
    __shared__ float4 red4[128];

    float acc[4] = {0.f, 0.f, 0.f, 0.f};
    const size_t vbase = (size_t)b * L_ * D_;
    int lbase = c * 256 + half;
    #pragma unroll 8
    for (int i = 0; i < 128; i++) {
        int l = lbase + i * 2;
        float a = att[b * L_ + l];
        float4 vv = *reinterpret_cast<const float4*>(v + vbase + (size_t)l * D_ + dt);
        acc[0] += a * vv.x; acc[1] += a * vv.y;
        acc[2] += a * vv.z; acc[3] += a * vv.w;
    }
    if (half) red4[t & 127] = make_float4(acc[0], acc[1], acc[2], acc[3]);
    __syncthreads();
    if (!half) {
        float4 r = red4[t];
        float* dst = ctx + b * D_ + dt;
        atomicAdd(dst + 0, acc[0] + r.x);
        atomicAdd(dst + 1, acc[1] + r.y);
        atomicAdd(dst + 2, acc[2] + r.z);
        atomicAdd(dst + 3, acc[3] + r.w);
    }
}

extern "C" void kernel_launch(void* const* d_in, const int* in_sizes, int n_in,
                              void* d_out, int out_size, void* d_ws, size_t ws_size,
                              hipStream_t stream) {
    const float* q = (const float*)d_in[0];
    const float* k = (const float*)d_in[1];
    const float* v = (const float*)d_in[2];
    float* out     = (float*)d_out;
    float* ctx_out = out;              // 32*512 fp32
    float* att_out = out + B_ * D_;    // 32*8192 fp32

    float* scores = (float*)d_ws;      // B_*L_ fp32 = 1 MiB

    k_scores     <<<B_ * (L_ / 64), 256,  0, stream>>>(q, k, scores);
    k_softmax2   <<<B_,             1024, 0, stream>>>(scores, att_out, ctx_out);
    k_ctx_partial<<<B_ * 32,        256,  0, stream>>>(v, att_out, ctx_out);
}

// Round 6
// 176.513 us; speedup vs baseline: 1.1760x; 1.1435x over previous
//
#include <hip/hip_runtime.h>
#include <hip/hip_bf16.h>
#include <stdint.h>

#define B_ 32
#define L_ 8192
#define D_ 512

typedef float vf4 __attribute__((ext_vector_type(4)));

__device__ __forceinline__ vf4 ntload4(const float* p) {
    return __builtin_nontemporal_load(reinterpret_cast<const vf4*>(p));
}

// K1: scores[b][l] = sum_d q[b][d] * k[b][l][d]   (fp32 inputs)
// grid = B_*(L_/64) = 4096 blocks, block = 256 (4 waves), each wave 16 rows.
// Per row: 64 lanes x 2 float4 = 512 floats = the whole D.
__global__ __launch_bounds__(256) void k_scores(const float* __restrict__ q,
                                                const float* __restrict__ k,
                                                float* __restrict__ scores) {
    int blk  = blockIdx.x;
    int b    = blk >> 7;            // 128 chunks per batch
    int l0   = (blk & 127) << 6;    // chunk * 64 rows
    int wave = threadIdx.x >> 6;
    int lane = threadIdx.x & 63;

    vf4 q0 = *reinterpret_cast<const vf4*>(q + b * D_ + lane * 4);
    vf4 q1 = *reinterpret_cast<const vf4*>(q + b * D_ + 256 + lane * 4);

    const size_t kbase = (size_t)b * L_ * D_;
    #pragma unroll 8
    for (int i = 0; i < 16; i++) {
        int l = l0 + i * 4 + wave;  // 4 waves read 4 adjacent 2 KiB rows
        const float* kr = k + kbase + (size_t)l * D_;
        vf4 a0 = ntload4(kr + lane * 4);
        vf4 a1 = ntload4(kr + 256 + lane * 4);
        float s = a0.x * q0.x + a0.y * q0.y + a0.z * q0.z + a0.w * q0.w
                + a1.x * q1.x + a1.y * q1.y + a1.z * q1.z + a1.w * q1.w;
        #pragma unroll
        for (int off = 32; off; off >>= 1) s += __shfl_xor(s, off, 64);
        if (lane == 0) scores[b * L_ + l] = s;
    }
}

// K2: double softmax over L per batch. 32 blocks x 1024 threads, 8 elems/thread.
// Writes att (fp32) to d_out only; also zeroes ctx[b] for K3's atomics.
__global__ __launch_bounds__(1024) void k_softmax2(const float* __restrict__ sc,
                                                   float* __restrict__ att_out,
                                                   float* __restrict__ ctx) {
    int b = blockIdx.x;
    int t = threadIdx.x;
    int wid = t >> 6, lane = t & 63;
    __shared__ float red[16];

    if (t < D_) ctx[b * D_ + t] = 0.f;   // stream-ordered before K3's atomicAdd

    float s[8];
    #pragma unroll
    for (int j = 0; j < 8; j++) s[j] = sc[b * L_ + t + j * 1024];

    // ---- max over L ----
    float m = s[0];
    #pragma unroll
    for (int j = 1; j < 8; j++) m = fmaxf(m, s[j]);
    #pragma unroll
    for (int off = 32; off; off >>= 1) m = fmaxf(m, __shfl_xor(m, off, 64));
    if (lane == 0) red[wid] = m;
    __syncthreads();
    m = red[0];
    #pragma unroll
    for (int i = 1; i < 16; i++) m = fmaxf(m, red[i]);
    __syncthreads();

    // ---- Z = sum exp(s - m) ----
    float e[8]; float sum = 0.f;
    #pragma unroll
    for (int j = 0; j < 8; j++) { e[j] = expf(s[j] - m); sum += e[j]; }
    #pragma unroll
    for (int off = 32; off; off >>= 1) sum += __shfl_xor(sum, off, 64);
    if (lane == 0) red[wid] = sum;
    __syncthreads();
    float Z = 0.f;
    #pragma unroll
    for (int i = 0; i < 16; i++) Z += red[i];
    __syncthreads();

    float invZ = 1.f / Z;
    // max of att_weights sits at the argmax of scores: exp(0)/Z = invZ
    float maxw = invZ;

    // ---- second softmax ----
    float p[8]; float sum2 = 0.f;
    #pragma unroll
    for (int j = 0; j < 8; j++) { p[j] = expf(e[j] * invZ - maxw); sum2 += p[j]; }
    #pragma unroll
    for (int off = 32; off; off >>= 1) sum2 += __shfl_xor(sum2, off, 64);
    if (lane == 0) red[wid] = sum2;
    __syncthreads();
    float S2 = 0.f;
    #pragma unroll
    for (int i = 0; i < 16; i++) S2 += red[i];

    float invS2 = 1.f / S2;
    #pragma unroll
    for (int j = 0; j < 8; j++) {
        att_out[b * L_ + t + j * 1024] = p[j] * invS2;
    }
}

// K3: ctx accumulation (fp32 V), fused reduction. grid = B_*32, block 256.
// Block = (b, chunk c of 256 L-rows). Threads 0..127 even rows, 128..255 odd.
// Thread covers d = (t&127)*4..+3. Block-level LDS reduce, then 4 atomicAdds
// per thread (t<128) into ctx — 32 blocks/b contend per address, ~1 us total.
__global__ __launch_bounds__(256) void k_ctx_partial(const float* __restrict__ v,
                                                     const float* __restrict__ att,
                                                     float* __restrict__ ctx) {
    int blk  = blockIdx.x;
    int b    = blk >> 5;
    int c    = blk & 31;
    int t    = threadIdx.x;
    int half = t >> 7;            // 0 or 1
    int dt   = (t & 127) * 4;
    __shared__ float4 red4[128];

    float acc[4] = {0.f, 0.f, 0.f, 0.f};
    const size_t vbase = (size_t)b * L_ * D_;
    int lbase = c * 256 + half;
    #pragma unroll 16
    for (int i = 0; i < 128; i++) {
        int l = lbase + i * 2;
        float a = __builtin_nontemporal_load(att + b * L_ + l);
        vf4 vv = ntload4(v + vbase + (size_t)l * D_ + dt);
        acc[0] += a * vv.x; acc[1] += a * vv.y;
        acc[2] += a * vv.z; acc[3] += a * vv.w;
    }
    if (half) red4[t & 127] = make_float4(acc[0], acc[1], acc[2], acc[3]);
    __syncthreads();
    if (!half) {
        float4 r = red4[t];
        float* dst = ctx + b * D_ + dt;
        atomicAdd(dst + 0, acc[0] + r.x);
        atomicAdd(dst + 1, acc[1] + r.y);
        atomicAdd(dst + 2, acc[2] + r.z);
        atomicAdd(dst + 3, acc[3] + r.w);
    }
}

extern "C" void kernel_launch(void* const* d_in, const int* in_sizes, int n_in,
                              void* d_out, int out_size, void* d_ws, size_t ws_size,
                              hipStream_t stream) {
    const float* q = (const float*)d_in[0];
    const float* k = (const float*)d_in[1];
    const float* v = (const float*)d_in[2];
    float* out     = (float*)d_out;
    float* ctx_out = out;              // 32*512 fp32
    float* att_out = out + B_ * D_;    // 32*8192 fp32

    float* scores = (float*)d_ws;      // B_*L_ fp32 = 1 MiB

    k_scores     <<<B_ * (L_ / 64), 256,  0, stream>>>(q, k, scores);
    k_softmax2   <<<B_,             1024, 0, stream>>>(scores, att_out, ctx_out);
    k_ctx_partial<<<B_ * 32,        256,  0, stream>>>(v, att_out, ctx_out);
}